// Round 12
// baseline (84.692 us; speedup 1.0000x reference)
//
#include <hip/hip_runtime.h>
#include <math.h>

#define KK 512
#define DD 512
#define HH 512
#define PD 128
#define KM1 511
#define LN_EPS 1e-5f
#define NCHUNK 4
#define CHUNK_T 128

typedef __attribute__((ext_vector_type(8))) short sh8;
typedef __attribute__((ext_vector_type(4))) short sh4;
typedef __attribute__((ext_vector_type(4))) float fx4;

#define MFMA16(a, b, c) __builtin_amdgcn_mfma_f32_16x16x32_bf16(a, b, c, 0, 0, 0)

__device__ __forceinline__ float wave_reduce_sum(float v) {
    #pragma unroll
    for (int off = 32; off > 0; off >>= 1)
        v += __shfl_xor(v, off, 64);
    return v;
}

__device__ __forceinline__ float half_reduce_sum(float v) {
    #pragma unroll
    for (int off = 16; off > 0; off >>= 1)
        v += __shfl_xor(v, off, 64);
    return v;
}

__device__ __forceinline__ short f2bf(float f) {
    unsigned u = __float_as_uint(f);
    u += 0x7fff + ((u >> 16) & 1);          // round-to-nearest-even
    return (short)(u >> 16);
}

__device__ __forceinline__ sh8 load_cvt8(const float* p) {
    float4 v0 = *(const float4*)p;
    float4 v1 = *(const float4*)(p + 4);
    sh8 r;
    r[0] = f2bf(v0.x); r[1] = f2bf(v0.y); r[2] = f2bf(v0.z); r[3] = f2bf(v0.w);
    r[4] = f2bf(v1.x); r[5] = f2bf(v1.y); r[6] = f2bf(v1.z); r[7] = f2bf(v1.w);
    return r;
}

// ---- sab only: sa[k], sb[k] (must precede pair_pass) ----
__global__ __launch_bounds__(256) void sab_kernel(
    const float* __restrict__ x, const float* __restrict__ W_att,
    float* __restrict__ sa, float* __restrict__ sb) {
    int w = threadIdx.x >> 6, lane = threadIdx.x & 63;
    int k = blockIdx.x * 4 + w;
    const float4* xr = (const float4*)(x + (size_t)k * DD);
    const float4* wa = (const float4*)(W_att);
    const float4* wb = (const float4*)(W_att + DD);
    float pa = 0.f, pb = 0.f;
    #pragma unroll
    for (int i = 0; i < 2; i++) {
        float4 xv = xr[lane + i * 64];
        float4 av = wa[lane + i * 64];
        float4 bv = wb[lane + i * 64];
        pa += xv.x * av.x + xv.y * av.y + xv.z * av.z + xv.w * av.w;
        pb += xv.x * bv.x + xv.y * bv.y + xv.z * bv.z + xv.w * bv.w;
    }
    pa = wave_reduce_sum(pa);
    pb = wave_reduce_sum(pb);
    if (lane == 0) { sa[k] = pa; sb[k] = pb; }
}

// ---- pair_pass + piggybacked weight-cvt (288) + oj GEMM (64 blocks) ----
// grid: [0,2048) pair | [2048,2336) W_pair/W1/W2 cvt | [2336,2400) ojT = (x·W_obj^T+b_obj)^T
__global__ __launch_bounds__(512) void pair_mega(
    const float* __restrict__ pf, const float* __restrict__ sa,
    const float* __restrict__ sb, const float* __restrict__ W_att,
    const float* __restrict__ b_att, short* __restrict__ Ab,
    float* __restrict__ apf_part, float* __restrict__ asum_part,
    const float* __restrict__ W_pair, const float* __restrict__ W1,
    const float* __restrict__ W2, short* __restrict__ W_pairb,
    short* __restrict__ W1b, short* __restrict__ W2b,
    const float* __restrict__ x, const float* __restrict__ W_obj,
    const float* __restrict__ b_obj, short* __restrict__ ojT) {
    int bid = blockIdx.x;
    int tid = threadIdx.x;
    __shared__ float smemf[4608];          // 18432 B, shared by both branches
    if (bid < 2048) {
        int k = bid >> 2;
        int chunk = bid & 3;
        int tbase = chunk * CHUNK_T;
        int w = tid >> 6, lane = tid & 63;
        int h = lane >> 5, c = lane & 31;
        int g = w * 2 + h;

        float* alpha_s = smemf;            // 128
        float* apf_s   = smemf + 128;      // 16*128
        float* asum_s  = smemf + 128 + 2048; // 16

        float4 wc4 = ((const float4*)(W_att + 2 * DD))[c];
        float sak = sa[k];
        float batt = b_att[0];
        const float4* pfk = (const float4*)(pf + (size_t)k * KM1 * PD);

        float4 v[8];
        int tr[8];
        #pragma unroll
        for (int it = 0; it < 8; it++) {
            int t = tbase + it * 16 + g;
            tr[it] = t;
            int tc = t < KM1 ? t : KM1 - 1;
            v[it] = pfk[(size_t)tc * 32 + c];
        }

        float a0 = 0.f, a1 = 0.f, a2 = 0.f, a3 = 0.f, asl = 0.f;
        #pragma unroll
        for (int it = 0; it < 8; it++) {
            float part = v[it].x * wc4.x + v[it].y * wc4.y + v[it].z * wc4.z + v[it].w * wc4.w;
            part = half_reduce_sum(part);
            int t = tr[it];
            int j = t + (t >= k);
            int jj = j < KK ? j : KK - 1;
            float z = sak + sb[jj] + part + batt;
            float alpha = (t < KM1) ? 1.f / (1.f + __expf(-z)) : 0.f;
            if (c == 0) alpha_s[it * 16 + g] = alpha;
            a0 += alpha * v[it].x;
            a1 += alpha * v[it].y;
            a2 += alpha * v[it].z;
            a3 += alpha * v[it].w;
            asl += alpha;
        }

        apf_s[g * 128 + 4 * c + 0] = a0;
        apf_s[g * 128 + 4 * c + 1] = a1;
        apf_s[g * 128 + 4 * c + 2] = a2;
        apf_s[g * 128 + 4 * c + 3] = a3;
        if (c == 0) asum_s[g] = asl;
        __syncthreads();
        if (tid < PD) {
            float s = 0.f;
            #pragma unroll
            for (int i = 0; i < 16; i++) s += apf_s[i * 128 + tid];
            apf_part[((size_t)chunk * KK + k) * PD + tid] = s;
        }
        if (tid < CHUNK_T) {
            int tt = tbase + tid;
            if (tt < KM1) {
                int j = tt + (tt >= k);
                Ab[(size_t)k * KK + j] = f2bf(alpha_s[tid]);
            }
        }
        if (tid == 0) {
            float s = 0.f;
            #pragma unroll
            for (int i = 0; i < 16; i++) s += asum_s[i];
            asum_part[(size_t)chunk * KK + k] = s;
            if (chunk == 0) Ab[(size_t)k * KK + k] = 0;
        }
    } else if (bid < 2336) {
        // W_pair/W1/W2 bf16 conversion: 288 blocks x 512 thr = 147456 float4 groups
        int i = (bid - 2048) * 512 + tid;
        const float* src; short* dst; int j;
        if (i < 16384)       { src = W_pair; dst = W_pairb; j = i; }
        else if (i < 81920)  { src = W1;     dst = W1b;     j = i - 16384; }
        else                 { src = W2;     dst = W2b;     j = i - 81920; }
        float4 v = ((const float4*)src)[j];
        sh4 s;
        s[0] = f2bf(v.x); s[1] = f2bf(v.y); s[2] = f2bf(v.z); s[3] = f2bf(v.w);
        ((sh4*)dst)[j] = s;
    } else {
        // oj GEMM: 64 blocks, 64x64 tile, 8 waves (2 row x 4 col), writes ojT bf16
        int tb = bid - 2336;
        int m0 = (tb >> 3) * 64, n0 = (tb & 7) * 64;
        int w = tid >> 6, l = tid & 63;
        int wr = w >> 2, wc = w & 3;
        int lr = l & 15, lk = (l >> 4) * 8;
        int mw = m0 + wr * 32, nw = n0 + wc * 16;
        fx4 acc[2] = {};
        for (int k0 = 0; k0 < DD; k0 += 32) {
            sh8 a0 = load_cvt8(&x[(size_t)(mw + lr) * DD + k0 + lk]);
            sh8 a1 = load_cvt8(&x[(size_t)(mw + 16 + lr) * DD + k0 + lk]);
            sh8 b  = load_cvt8(&W_obj[(size_t)(nw + lr) * DD + k0 + lk]);
            acc[0] = MFMA16(a0, b, acc[0]);
            acc[1] = MFMA16(a1, b, acc[1]);
        }
        short* tileS = (short*)smemf;      // [64][72]
        int lm4 = (l >> 4) * 4;
        int col = wc * 16 + lr;            // local h
        float bo = b_obj[n0 + col];
        #pragma unroll
        for (int rf = 0; rf < 2; rf++) {
            #pragma unroll
            for (int r = 0; r < 4; r++) {
                int rowl = wr * 32 + rf * 16 + lm4 + r;   // local j
                tileS[col * 72 + rowl] = f2bf(acc[rf][r] + bo);
            }
        }
        __syncthreads();
        int row = tid >> 3, c8 = tid & 7;
        *(sh8*)&ojT[(size_t)(n0 + row) * KK + m0 + c8 * 8] =
            *(sh8*)&tileS[row * 72 + c8 * 8];
    }
}

// ---- k_msg: msg = A·oj + apf·W_pair^T (R11 geometry; A,ojT bf16) ----
__global__ __launch_bounds__(128) void k_msg(const short* __restrict__ Ab,
                                             const short* __restrict__ ojT,
                                             const float* __restrict__ apf_part,
                                             const short* __restrict__ W_pairb,
                                             float* __restrict__ msg) {
    int m0 = blockIdx.y * 32, n0 = blockIdx.x * 32;
    int tid = threadIdx.x;
    int wv = tid >> 6, l = tid & 63;
    int lr = l & 15, lk = (l >> 4) * 8;
    int mw = m0 + wv * 16;
    fx4 acc[2] = {};
    for (int k0 = 0; k0 < KK; k0 += 32) {
        sh8 a  = *(const sh8*)&Ab[(size_t)(mw + lr) * KK + k0 + lk];
        sh8 b0 = *(const sh8*)&ojT[(size_t)(n0 + lr) * KK + k0 + lk];
        sh8 b1 = *(const sh8*)&ojT[(size_t)(n0 + 16 + lr) * KK + k0 + lk];
        acc[0] = MFMA16(a, b0, acc[0]);
        acc[1] = MFMA16(a, b1, acc[1]);
    }
    for (int k0 = 0; k0 < PD; k0 += 32) {
        int p = k0 + lk;
        int row = mw + lr;
        float4 u0 = make_float4(0.f, 0.f, 0.f, 0.f);
        float4 u1 = make_float4(0.f, 0.f, 0.f, 0.f);
        #pragma unroll
        for (int cc = 0; cc < NCHUNK; cc++) {
            const float* pp = &apf_part[((size_t)cc * KK + row) * PD + p];
            float4 w0 = *(const float4*)pp;
            float4 w1 = *(const float4*)(pp + 4);
            u0.x += w0.x; u0.y += w0.y; u0.z += w0.z; u0.w += w0.w;
            u1.x += w1.x; u1.y += w1.y; u1.z += w1.z; u1.w += w1.w;
        }
        sh8 a;
        a[0] = f2bf(u0.x); a[1] = f2bf(u0.y); a[2] = f2bf(u0.z); a[3] = f2bf(u0.w);
        a[4] = f2bf(u1.x); a[5] = f2bf(u1.y); a[6] = f2bf(u1.z); a[7] = f2bf(u1.w);
        sh8 b0 = *(const sh8*)&W_pairb[(size_t)(n0 + lr) * PD + p];
        sh8 b1 = *(const sh8*)&W_pairb[(size_t)(n0 + 16 + lr) * PD + p];
        acc[0] = MFMA16(a, b0, acc[0]);
        acc[1] = MFMA16(a, b1, acc[1]);
    }
    __shared__ float tile[32][36];
    int lm4 = (l >> 4) * 4;
    #pragma unroll
    for (int cf = 0; cf < 2; cf++)
        #pragma unroll
        for (int r = 0; r < 4; r++)
            tile[wv * 16 + lm4 + r][cf * 16 + lr] = acc[cf][r];
    __syncthreads();
    for (int q = tid; q < 256; q += 128) {
        int row = q >> 3, c4 = q & 7;
        *(float4*)&msg[(size_t)(m0 + row) * HH + n0 + c4 * 4] = *(float4*)&tile[row][c4 * 4];
    }
}

// ---- ln1: out1 = LN(x + (msg + asum*b_pair)/511), + bf16 copy ----
__global__ __launch_bounds__(128) void ln1_kernel(
    const float* __restrict__ msg, const float* __restrict__ x,
    const float* __restrict__ asum_part, const float* __restrict__ b_pair,
    const float* __restrict__ ln_g, const float* __restrict__ ln_b,
    float* __restrict__ out1, short* __restrict__ out1b) {
    int k = blockIdx.x;
    int tid = threadIdx.x;
    int wv = tid >> 6, l = tid & 63;
    float as = asum_part[k] + asum_part[KK + k] + asum_part[2 * KK + k] + asum_part[3 * KK + k];
    float4 m  = ((const float4*)(msg + (size_t)k * HH))[tid];
    float4 bp = ((const float4*)b_pair)[tid];
    float4 xr = ((const float4*)(x + (size_t)k * DD))[tid];
    const float inv = 1.0f / (float)KM1;
    float4 v;
    v.x = xr.x + (m.x + as * bp.x) * inv;
    v.y = xr.y + (m.y + as * bp.y) * inv;
    v.z = xr.z + (m.z + as * bp.z) * inv;
    v.w = xr.w + (m.w + as * bp.w) * inv;
    float s1 = v.x + v.y + v.z + v.w;
    float s2 = v.x * v.x + v.y * v.y + v.z * v.z + v.w * v.w;
    s1 = wave_reduce_sum(s1);
    s2 = wave_reduce_sum(s2);
    __shared__ float r1[2], r2[2];
    if (l == 0) { r1[wv] = s1; r2[wv] = s2; }
    __syncthreads();
    float S1 = r1[0] + r1[1], S2 = r2[0] + r2[1];
    float mu = S1 * (1.0f / HH);
    float var = S2 * (1.0f / HH) - mu * mu;
    float rs = rsqrtf(var + LN_EPS);
    float4 g4 = ((const float4*)ln_g)[tid];
    float4 b4 = ((const float4*)ln_b)[tid];
    float4 o;
    o.x = g4.x * (v.x - mu) * rs + b4.x;
    o.y = g4.y * (v.y - mu) * rs + b4.y;
    o.z = g4.z * (v.z - mu) * rs + b4.z;
    o.w = g4.w * (v.w - mu) * rs + b4.w;
    ((float4*)(out1 + (size_t)k * HH))[tid] = o;
    sh4 s;
    s[0] = f2bf(o.x); s[1] = f2bf(o.y); s[2] = f2bf(o.z); s[3] = f2bf(o.w);
    ((sh4*)(out1b + (size_t)k * HH))[tid] = s;
}

// ---- k_ffn1: h1b = bf16(relu(out1·W1^T + b1)), R8 geometry ----
__global__ __launch_bounds__(128) void k_ffn1(const short* __restrict__ out1b,
                                              const short* __restrict__ W1b,
                                              const float* __restrict__ b1,
                                              short* __restrict__ h1b) {
    int m0 = blockIdx.y * 32, n0 = blockIdx.x * 32;
    int tid = threadIdx.x;
    int wv = tid >> 6, l = tid & 63;
    int lr = l & 15, lk = (l >> 4) * 8;
    int mw = m0 + wv * 16;
    fx4 acc[2] = {};
    for (int k0 = 0; k0 < HH; k0 += 32) {
        sh8 a  = *(const sh8*)&out1b[(size_t)(mw + lr) * HH + k0 + lk];
        sh8 b0 = *(const sh8*)&W1b[(size_t)(n0 + lr) * HH + k0 + lk];
        sh8 b1 = *(const sh8*)&W1b[(size_t)(n0 + 16 + lr) * HH + k0 + lk];
        acc[0] = MFMA16(a, b0, acc[0]);
        acc[1] = MFMA16(a, b1, acc[1]);
    }
    __shared__ short tile[32][40];
    int lm4 = (l >> 4) * 4;
    #pragma unroll
    for (int cf = 0; cf < 2; cf++) {
        int col = cf * 16 + lr;
        float bb = b1[n0 + col];
        #pragma unroll
        for (int r = 0; r < 4; r++)
            tile[wv * 16 + lm4 + r][col] = f2bf(fmaxf(acc[cf][r] + bb, 0.f));
    }
    __syncthreads();
    int row = tid >> 2, co = (tid & 3) * 8;
    *(sh8*)&h1b[(size_t)(m0 + row) * HH + n0 + co] = *(sh8*)&tile[row][co];
}

// ---- k_ffn2: ffn = h1·W2^T (fp32 out), R8 geometry ----
__global__ __launch_bounds__(128) void k_ffn2(const short* __restrict__ h1b,
                                              const short* __restrict__ W2b,
                                              float* __restrict__ ffn) {
    int m0 = blockIdx.y * 32, n0 = blockIdx.x * 32;
    int tid = threadIdx.x;
    int wv = tid >> 6, l = tid & 63;
    int lr = l & 15, lk = (l >> 4) * 8;
    int mw = m0 + wv * 16;
    fx4 acc[2] = {};
    for (int k0 = 0; k0 < HH; k0 += 32) {
        sh8 a  = *(const sh8*)&h1b[(size_t)(mw + lr) * HH + k0 + lk];
        sh8 b0 = *(const sh8*)&W2b[(size_t)(n0 + lr) * HH + k0 + lk];
        sh8 b1 = *(const sh8*)&W2b[(size_t)(n0 + 16 + lr) * HH + k0 + lk];
        acc[0] = MFMA16(a, b0, acc[0]);
        acc[1] = MFMA16(a, b1, acc[1]);
    }
    __shared__ float tile[32][36];
    int lm4 = (l >> 4) * 4;
    #pragma unroll
    for (int cf = 0; cf < 2; cf++)
        #pragma unroll
        for (int r = 0; r < 4; r++)
            tile[wv * 16 + lm4 + r][cf * 16 + lr] = acc[cf][r];
    __syncthreads();
    for (int q = tid; q < 256; q += 128) {
        int row = q >> 3, c4 = q & 7;
        *(float4*)&ffn[(size_t)(m0 + row) * HH + n0 + c4 * 4] = *(float4*)&tile[row][c4 * 4];
    }
}

// ---- ln2: out = LN(out1 + ffn + b2) ----
__global__ __launch_bounds__(128) void ln2_kernel(
    const float* __restrict__ ffn, const float* __restrict__ out1,
    const float* __restrict__ b2, const float* __restrict__ ln_g,
    const float* __restrict__ ln_b, float* __restrict__ out) {
    int k = blockIdx.x;
    int tid = threadIdx.x;
    int wv = tid >> 6, l = tid & 63;
    float4 f  = ((const float4*)(ffn + (size_t)k * HH))[tid];
    float4 xr = ((const float4*)(out1 + (size_t)k * HH))[tid];
    float4 bb = ((const float4*)b2)[tid];
    float4 v;
    v.x = xr.x + f.x + bb.x;
    v.y = xr.y + f.y + bb.y;
    v.z = xr.z + f.z + bb.z;
    v.w = xr.w + f.w + bb.w;
    float s1 = v.x + v.y + v.z + v.w;
    float s2 = v.x * v.x + v.y * v.y + v.z * v.z + v.w * v.w;
    s1 = wave_reduce_sum(s1);
    s2 = wave_reduce_sum(s2);
    __shared__ float r1[2], r2[2];
    if (l == 0) { r1[wv] = s1; r2[wv] = s2; }
    __syncthreads();
    float S1 = r1[0] + r1[1], S2 = r2[0] + r2[1];
    float mu = S1 * (1.0f / HH);
    float var = S2 * (1.0f / HH) - mu * mu;
    float rs = rsqrtf(var + LN_EPS);
    float4 g4 = ((const float4*)ln_g)[tid];
    float4 b4 = ((const float4*)ln_b)[tid];
    float4 o;
    o.x = g4.x * (v.x - mu) * rs + b4.x;
    o.y = g4.y * (v.y - mu) * rs + b4.y;
    o.z = g4.z * (v.z - mu) * rs + b4.z;
    o.w = g4.w * (v.w - mu) * rs + b4.w;
    ((float4*)(out + (size_t)k * HH))[tid] = o;
}

extern "C" void kernel_launch(void* const* d_in, const int* in_sizes, int n_in,
                              void* d_out, int out_size, void* d_ws, size_t ws_size,
                              hipStream_t stream) {
    const float* x          = (const float*)d_in[0];
    const float* pair_feats = (const float*)d_in[1];
    const float* W_att      = (const float*)d_in[2];
    const float* b_att      = (const float*)d_in[3];
    const float* W_obj      = (const float*)d_in[4];
    const float* b_obj      = (const float*)d_in[5];
    const float* W_pair     = (const float*)d_in[6];
    const float* b_pair     = (const float*)d_in[7];
    const float* ln_g       = (const float*)d_in[8];
    const float* ln_b       = (const float*)d_in[9];
    const float* W1         = (const float*)d_in[10];
    const float* b1         = (const float*)d_in[11];
    const float* W2         = (const float*)d_in[12];
    const float* b2         = (const float*)d_in[13];
    float* out = (float*)d_out;

    const size_t MAT = (size_t)KK * HH;       // 262144
    float* ws        = (float*)d_ws;
    float* sa        = ws;                                  // 512
    float* sb        = sa + KK;                             // 512
    float* asum_part = sb + KK;                             // 4*512
    float* apf_part  = asum_part + NCHUNK * KK;             // 4*512*128
    float* msg       = apf_part + (size_t)NCHUNK * KK * PD; // MAT
    float* out1      = msg + MAT;                           // MAT
    float* ffn       = out1 + MAT;                          // MAT
    short* Ab        = (short*)(ffn + MAT);                 // MAT bf16
    short* ojT       = Ab + MAT;                            // MAT
    short* W_pairb   = ojT + MAT;                           // 512*128
    short* W1b       = W_pairb + (size_t)HH * PD;           // MAT
    short* W2b       = W1b + MAT;                           // MAT
    short* out1b     = W2b + MAT;                           // MAT
    short* h1b       = out1b + MAT;                         // MAT

    sab_kernel<<<128, 256, 0, stream>>>(x, W_att, sa, sb);
    pair_mega<<<2400, 512, 0, stream>>>(pair_feats, sa, sb, W_att, b_att,
                                        Ab, apf_part, asum_part,
                                        W_pair, W1, W2, W_pairb, W1b, W2b,
                                        x, W_obj, b_obj, ojT);
    k_msg<<<dim3(16, 16), 128, 0, stream>>>(Ab, ojT, apf_part, W_pairb, msg);
    ln1_kernel<<<512, 128, 0, stream>>>(msg, x, asum_part, b_pair, ln_g, ln_b, out1, out1b);
    k_ffn1<<<dim3(16, 16), 128, 0, stream>>>(out1b, W1b, b1, h1b);
    k_ffn2<<<dim3(16, 16), 128, 0, stream>>>(h1b, W2b, ffn);
    ln2_kernel<<<512, 128, 0, stream>>>(ffn, out1, b2, ln_g, ln_b, out);
}

// Round 13
// 60.030 us; speedup vs baseline: 1.4108x; 1.4108x over previous
//
#include <hip/hip_runtime.h>
#include <math.h>

#define KK 512
#define DD 512
#define HH 512
#define PD 128
#define KM1 511
#define LN_EPS 1e-5f
#define NCHUNK 4
#define CHUNK_T 128

typedef __attribute__((ext_vector_type(8))) short sh8;
typedef __attribute__((ext_vector_type(4))) short sh4;
typedef __attribute__((ext_vector_type(4))) float fx4;

#define MFMA16(a, b, c) __builtin_amdgcn_mfma_f32_16x16x32_bf16(a, b, c, 0, 0, 0)

__device__ __forceinline__ float wave_reduce_sum(float v) {
    #pragma unroll
    for (int off = 32; off > 0; off >>= 1)
        v += __shfl_xor(v, off, 64);
    return v;
}

__device__ __forceinline__ float half_reduce_sum(float v) {
    #pragma unroll
    for (int off = 16; off > 0; off >>= 1)
        v += __shfl_xor(v, off, 64);
    return v;
}

__device__ __forceinline__ short f2bf(float f) {
    unsigned u = __float_as_uint(f);
    u += 0x7fff + ((u >> 16) & 1);          // round-to-nearest-even
    return (short)(u >> 16);
}

__device__ __forceinline__ sh8 load_cvt8(const float* p) {
    float4 v0 = *(const float4*)p;
    float4 v1 = *(const float4*)(p + 4);
    sh8 r;
    r[0] = f2bf(v0.x); r[1] = f2bf(v0.y); r[2] = f2bf(v0.z); r[3] = f2bf(v0.w);
    r[4] = f2bf(v1.x); r[5] = f2bf(v1.y); r[6] = f2bf(v1.z); r[7] = f2bf(v1.w);
    return r;
}

// ---- sab only: sa[k], sb[k] (must precede pair_pass) ----
__global__ __launch_bounds__(256) void sab_kernel(
    const float* __restrict__ x, const float* __restrict__ W_att,
    float* __restrict__ sa, float* __restrict__ sb) {
    int w = threadIdx.x >> 6, lane = threadIdx.x & 63;
    int k = blockIdx.x * 4 + w;
    const float4* xr = (const float4*)(x + (size_t)k * DD);
    const float4* wa = (const float4*)(W_att);
    const float4* wb = (const float4*)(W_att + DD);
    float pa = 0.f, pb = 0.f;
    #pragma unroll
    for (int i = 0; i < 2; i++) {
        float4 xv = xr[lane + i * 64];
        float4 av = wa[lane + i * 64];
        float4 bv = wb[lane + i * 64];
        pa += xv.x * av.x + xv.y * av.y + xv.z * av.z + xv.w * av.w;
        pb += xv.x * bv.x + xv.y * bv.y + xv.z * bv.z + xv.w * bv.w;
    }
    pa = wave_reduce_sum(pa);
    pb = wave_reduce_sum(pb);
    if (lane == 0) { sa[k] = pa; sb[k] = pb; }
}

// ---- pair_pass (R8 body) + piggybacked weight-cvt (416) + xT transpose (256) ----
// flattened grid: [0,2048) pair | [2048,2464) weight cvt | [2464,2720) xT tiles
__global__ __launch_bounds__(512) void pair_mega(
    const float* __restrict__ pf, const float* __restrict__ sa,
    const float* __restrict__ sb, const float* __restrict__ W_att,
    const float* __restrict__ b_att, short* __restrict__ Ab,
    float* __restrict__ apf_part, float* __restrict__ asum_part,
    const float* __restrict__ W_obj, const float* __restrict__ W_pair,
    const float* __restrict__ W1, const float* __restrict__ W2,
    short* __restrict__ W_objb, short* __restrict__ W_pairb,
    short* __restrict__ W1b, short* __restrict__ W2b,
    const float* __restrict__ x, short* __restrict__ xTb) {
    int bid = blockIdx.x;
    int tid = threadIdx.x;
    if (bid < 2048) {
        int k = bid >> 2;
        int chunk = bid & 3;
        int tbase = chunk * CHUNK_T;
        int w = tid >> 6, lane = tid & 63;
        int h = lane >> 5, c = lane & 31;
        int g = w * 2 + h;

        float4 wc4 = ((const float4*)(W_att + 2 * DD))[c];
        float sak = sa[k];
        float batt = b_att[0];
        const float4* pfk = (const float4*)(pf + (size_t)k * KM1 * PD);

        float4 v[8];
        int tr[8];
        #pragma unroll
        for (int it = 0; it < 8; it++) {
            int t = tbase + it * 16 + g;
            tr[it] = t;
            int tc = t < KM1 ? t : KM1 - 1;
            v[it] = pfk[(size_t)tc * 32 + c];
        }

        __shared__ float alpha_s[CHUNK_T];
        float a0 = 0.f, a1 = 0.f, a2 = 0.f, a3 = 0.f, asl = 0.f;
        #pragma unroll
        for (int it = 0; it < 8; it++) {
            float part = v[it].x * wc4.x + v[it].y * wc4.y + v[it].z * wc4.z + v[it].w * wc4.w;
            part = half_reduce_sum(part);
            int t = tr[it];
            int j = t + (t >= k);
            int jj = j < KK ? j : KK - 1;
            float z = sak + sb[jj] + part + batt;
            float alpha = (t < KM1) ? 1.f / (1.f + __expf(-z)) : 0.f;
            if (c == 0) alpha_s[it * 16 + g] = alpha;
            a0 += alpha * v[it].x;
            a1 += alpha * v[it].y;
            a2 += alpha * v[it].z;
            a3 += alpha * v[it].w;
            asl += alpha;
        }

        __shared__ float apf_s[16][128];
        __shared__ float asum_s[16];
        apf_s[g][4 * c + 0] = a0;
        apf_s[g][4 * c + 1] = a1;
        apf_s[g][4 * c + 2] = a2;
        apf_s[g][4 * c + 3] = a3;
        if (c == 0) asum_s[g] = asl;
        __syncthreads();
        if (tid < PD) {
            float s = 0.f;
            #pragma unroll
            for (int i = 0; i < 16; i++) s += apf_s[i][tid];
            apf_part[((size_t)chunk * KK + k) * PD + tid] = s;
        }
        if (tid < CHUNK_T) {
            int tt = tbase + tid;
            if (tt < KM1) {
                int j = tt + (tt >= k);
                Ab[(size_t)k * KK + j] = f2bf(alpha_s[tid]);
            }
        }
        if (tid == 0) {
            float s = 0.f;
            #pragma unroll
            for (int i = 0; i < 16; i++) s += asum_s[i];
            asum_part[(size_t)chunk * KK + k] = s;
            if (chunk == 0) Ab[(size_t)k * KK + k] = 0;
        }
    } else if (bid < 2464) {
        // weight bf16 conversion: 416 blocks x 512 threads = 212992 float4 groups
        int i = (bid - 2048) * 512 + tid;
        const float* src; short* dst; int j;
        if (i < 65536)       { src = W_obj;  dst = W_objb;  j = i; }
        else if (i < 81920)  { src = W_pair; dst = W_pairb; j = i - 65536; }
        else if (i < 147456) { src = W1;     dst = W1b;     j = i - 81920; }
        else                 { src = W2;     dst = W2b;     j = i - 147456; }
        float4 v = ((const float4*)src)[j];
        sh4 s;
        s[0] = f2bf(v.x); s[1] = f2bf(v.y); s[2] = f2bf(v.z); s[3] = f2bf(v.w);
        ((sh4*)dst)[j] = s;
    } else {
        // xTb[d][j] = bf16(x[j][d]), 256 tiles of 32x32, 512 threads (16 rows/pass)
        int tb = bid - 2464;
        int r0 = (tb >> 4) * 32, c0 = (tb & 15) * 32;
        int tx = tid & 31, ty = tid >> 5;      // ty 0..15
        __shared__ short tileT[32][33];
        #pragma unroll
        for (int i = 0; i < 2; i++) {
            int r = ty + i * 16;
            tileT[tx][r] = f2bf(x[(size_t)(r0 + r) * DD + c0 + tx]);
        }
        __syncthreads();
        #pragma unroll
        for (int i = 0; i < 2; i++) {
            int rr = ty + i * 16;
            xTb[(size_t)(c0 + rr) * KK + r0 + tx] = tileT[rr][tx];
        }
    }
}

// ---- k_y: yb = bf16(A · x)  (R8 geometry: 32x32 tile, 2 waves) ----
__global__ __launch_bounds__(128) void k_y(const short* __restrict__ Ab,
                                           const short* __restrict__ xTb,
                                           short* __restrict__ yb) {
    int m0 = blockIdx.y * 32, n0 = blockIdx.x * 32;
    int tid = threadIdx.x;
    int wv = tid >> 6, l = tid & 63;
    int lr = l & 15, lk = (l >> 4) * 8;
    int mw = m0 + wv * 16;
    fx4 acc[2] = {};
    for (int k0 = 0; k0 < KK; k0 += 32) {
        sh8 a  = *(const sh8*)&Ab[(size_t)(mw + lr) * KK + k0 + lk];
        sh8 b0 = *(const sh8*)&xTb[(size_t)(n0 + lr) * KK + k0 + lk];
        sh8 b1 = *(const sh8*)&xTb[(size_t)(n0 + 16 + lr) * KK + k0 + lk];
        acc[0] = MFMA16(a, b0, acc[0]);
        acc[1] = MFMA16(a, b1, acc[1]);
    }
    __shared__ short tile[32][40];
    int lm4 = (l >> 4) * 4;
    #pragma unroll
    for (int cf = 0; cf < 2; cf++)
        #pragma unroll
        for (int r = 0; r < 4; r++)
            tile[wv * 16 + lm4 + r][cf * 16 + lr] = f2bf(acc[cf][r]);
    __syncthreads();
    int row = tid >> 2, co = (tid & 3) * 8;
    *(sh8*)&yb[(size_t)(m0 + row) * KK + n0 + co] = *(sh8*)&tile[row][co];
}

// ---- k_msg: msg = y·W_obj^T + apf·W_pair^T (bf16 weights, R8 geometry) ----
__global__ __launch_bounds__(128) void k_msg(const short* __restrict__ yb,
                                             const short* __restrict__ W_objb,
                                             const float* __restrict__ apf_part,
                                             const short* __restrict__ W_pairb,
                                             float* __restrict__ msg) {
    int m0 = blockIdx.y * 32, n0 = blockIdx.x * 32;
    int tid = threadIdx.x;
    int wv = tid >> 6, l = tid & 63;
    int lr = l & 15, lk = (l >> 4) * 8;
    int mw = m0 + wv * 16;
    fx4 acc[2] = {};
    for (int k0 = 0; k0 < KK; k0 += 32) {
        sh8 a  = *(const sh8*)&yb[(size_t)(mw + lr) * KK + k0 + lk];
        sh8 b0 = *(const sh8*)&W_objb[(size_t)(n0 + lr) * DD + k0 + lk];
        sh8 b1 = *(const sh8*)&W_objb[(size_t)(n0 + 16 + lr) * DD + k0 + lk];
        acc[0] = MFMA16(a, b0, acc[0]);
        acc[1] = MFMA16(a, b1, acc[1]);
    }
    for (int k0 = 0; k0 < PD; k0 += 32) {
        int p = k0 + lk;
        int row = mw + lr;
        float4 u0 = make_float4(0.f, 0.f, 0.f, 0.f);
        float4 u1 = make_float4(0.f, 0.f, 0.f, 0.f);
        #pragma unroll
        for (int cc = 0; cc < NCHUNK; cc++) {
            const float* pp = &apf_part[((size_t)cc * KK + row) * PD + p];
            float4 w0 = *(const float4*)pp;
            float4 w1 = *(const float4*)(pp + 4);
            u0.x += w0.x; u0.y += w0.y; u0.z += w0.z; u0.w += w0.w;
            u1.x += w1.x; u1.y += w1.y; u1.z += w1.z; u1.w += w1.w;
        }
        sh8 a;
        a[0] = f2bf(u0.x); a[1] = f2bf(u0.y); a[2] = f2bf(u0.z); a[3] = f2bf(u0.w);
        a[4] = f2bf(u1.x); a[5] = f2bf(u1.y); a[6] = f2bf(u1.z); a[7] = f2bf(u1.w);
        sh8 b0 = *(const sh8*)&W_pairb[(size_t)(n0 + lr) * PD + p];
        sh8 b1 = *(const sh8*)&W_pairb[(size_t)(n0 + 16 + lr) * PD + p];
        acc[0] = MFMA16(a, b0, acc[0]);
        acc[1] = MFMA16(a, b1, acc[1]);
    }
    __shared__ float tile[32][36];
    int lm4 = (l >> 4) * 4;
    #pragma unroll
    for (int cf = 0; cf < 2; cf++)
        #pragma unroll
        for (int r = 0; r < 4; r++)
            tile[wv * 16 + lm4 + r][cf * 16 + lr] = acc[cf][r];
    __syncthreads();
    for (int q = tid; q < 256; q += 128) {
        int row = q >> 3, c4 = q & 7;
        *(float4*)&msg[(size_t)(m0 + row) * HH + n0 + c4 * 4] = *(float4*)&tile[row][c4 * 4];
    }
}

// ---- ln1: out1 = LN(x + (msg + asum*(b_pair+b_obj))/511), + bf16 copy ----
__global__ __launch_bounds__(128) void ln1_kernel(
    const float* __restrict__ msg, const float* __restrict__ x,
    const float* __restrict__ asum_part, const float* __restrict__ b_pair,
    const float* __restrict__ b_obj, const float* __restrict__ ln_g,
    const float* __restrict__ ln_b, float* __restrict__ out1,
    short* __restrict__ out1b) {
    int k = blockIdx.x;
    int tid = threadIdx.x;
    int wv = tid >> 6, l = tid & 63;
    float as = asum_part[k] + asum_part[KK + k] + asum_part[2 * KK + k] + asum_part[3 * KK + k];
    float4 m  = ((const float4*)(msg + (size_t)k * HH))[tid];
    float4 bp = ((const float4*)b_pair)[tid];
    float4 bo = ((const float4*)b_obj)[tid];
    float4 xr = ((const float4*)(x + (size_t)k * DD))[tid];
    const float inv = 1.0f / (float)KM1;
    float4 v;
    v.x = xr.x + (m.x + as * (bp.x + bo.x)) * inv;
    v.y = xr.y + (m.y + as * (bp.y + bo.y)) * inv;
    v.z = xr.z + (m.z + as * (bp.z + bo.z)) * inv;
    v.w = xr.w + (m.w + as * (bp.w + bo.w)) * inv;
    float s1 = v.x + v.y + v.z + v.w;
    float s2 = v.x * v.x + v.y * v.y + v.z * v.z + v.w * v.w;
    s1 = wave_reduce_sum(s1);
    s2 = wave_reduce_sum(s2);
    __shared__ float r1[2], r2[2];
    if (l == 0) { r1[wv] = s1; r2[wv] = s2; }
    __syncthreads();
    float S1 = r1[0] + r1[1], S2 = r2[0] + r2[1];
    float mu = S1 * (1.0f / HH);
    float var = S2 * (1.0f / HH) - mu * mu;
    float rs = rsqrtf(var + LN_EPS);
    float4 g4 = ((const float4*)ln_g)[tid];
    float4 b4 = ((const float4*)ln_b)[tid];
    float4 o;
    o.x = g4.x * (v.x - mu) * rs + b4.x;
    o.y = g4.y * (v.y - mu) * rs + b4.y;
    o.z = g4.z * (v.z - mu) * rs + b4.z;
    o.w = g4.w * (v.w - mu) * rs + b4.w;
    ((float4*)(out1 + (size_t)k * HH))[tid] = o;
    sh4 s;
    s[0] = f2bf(o.x); s[1] = f2bf(o.y); s[2] = f2bf(o.z); s[3] = f2bf(o.w);
    ((sh4*)(out1b + (size_t)k * HH))[tid] = s;
}

// ---- k_ffn1: h1b = bf16(relu(out1·W1^T + b1)), R8 geometry ----
__global__ __launch_bounds__(128) void k_ffn1(const short* __restrict__ out1b,
                                              const short* __restrict__ W1b,
                                              const float* __restrict__ b1,
                                              short* __restrict__ h1b) {
    int m0 = blockIdx.y * 32, n0 = blockIdx.x * 32;
    int tid = threadIdx.x;
    int wv = tid >> 6, l = tid & 63;
    int lr = l & 15, lk = (l >> 4) * 8;
    int mw = m0 + wv * 16;
    fx4 acc[2] = {};
    for (int k0 = 0; k0 < HH; k0 += 32) {
        sh8 a  = *(const sh8*)&out1b[(size_t)(mw + lr) * HH + k0 + lk];
        sh8 b0 = *(const sh8*)&W1b[(size_t)(n0 + lr) * HH + k0 + lk];
        sh8 b1 = *(const sh8*)&W1b[(size_t)(n0 + 16 + lr) * HH + k0 + lk];
        acc[0] = MFMA16(a, b0, acc[0]);
        acc[1] = MFMA16(a, b1, acc[1]);
    }
    __shared__ short tile[32][40];
    int lm4 = (l >> 4) * 4;
    #pragma unroll
    for (int cf = 0; cf < 2; cf++) {
        int col = cf * 16 + lr;
        float bb = b1[n0 + col];
        #pragma unroll
        for (int r = 0; r < 4; r++)
            tile[wv * 16 + lm4 + r][col] = f2bf(fmaxf(acc[cf][r] + bb, 0.f));
    }
    __syncthreads();
    int row = tid >> 2, co = (tid & 3) * 8;
    *(sh8*)&h1b[(size_t)(m0 + row) * HH + n0 + co] = *(sh8*)&tile[row][co];
}

// ---- k_ffn2: ffn = h1·W2^T (fp32 out), R8 geometry ----
__global__ __launch_bounds__(128) void k_ffn2(const short* __restrict__ h1b,
                                              const short* __restrict__ W2b,
                                              float* __restrict__ ffn) {
    int m0 = blockIdx.y * 32, n0 = blockIdx.x * 32;
    int tid = threadIdx.x;
    int wv = tid >> 6, l = tid & 63;
    int lr = l & 15, lk = (l >> 4) * 8;
    int mw = m0 + wv * 16;
    fx4 acc[2] = {};
    for (int k0 = 0; k0 < HH; k0 += 32) {
        sh8 a  = *(const sh8*)&h1b[(size_t)(mw + lr) * HH + k0 + lk];
        sh8 b0 = *(const sh8*)&W2b[(size_t)(n0 + lr) * HH + k0 + lk];
        sh8 b1 = *(const sh8*)&W2b[(size_t)(n0 + 16 + lr) * HH + k0 + lk];
        acc[0] = MFMA16(a, b0, acc[0]);
        acc[1] = MFMA16(a, b1, acc[1]);
    }
    __shared__ float tile[32][36];
    int lm4 = (l >> 4) * 4;
    #pragma unroll
    for (int cf = 0; cf < 2; cf++)
        #pragma unroll
        for (int r = 0; r < 4; r++)
            tile[wv * 16 + lm4 + r][cf * 16 + lr] = acc[cf][r];
    __syncthreads();
    for (int q = tid; q < 256; q += 128) {
        int row = q >> 3, c4 = q & 7;
        *(float4*)&ffn[(size_t)(m0 + row) * HH + n0 + c4 * 4] = *(float4*)&tile[row][c4 * 4];
    }
}

// ---- ln2: out = LN(out1 + ffn + b2) ----
__global__ __launch_bounds__(128) void ln2_kernel(
    const float* __restrict__ ffn, const float* __restrict__ out1,
    const float* __restrict__ b2, const float* __restrict__ ln_g,
    const float* __restrict__ ln_b, float* __restrict__ out) {
    int k = blockIdx.x;
    int tid = threadIdx.x;
    int wv = tid >> 6, l = tid & 63;
    float4 f  = ((const float4*)(ffn + (size_t)k * HH))[tid];
    float4 xr = ((const float4*)(out1 + (size_t)k * HH))[tid];
    float4 bb = ((const float4*)b2)[tid];
    float4 v;
    v.x = xr.x + f.x + bb.x;
    v.y = xr.y + f.y + bb.y;
    v.z = xr.z + f.z + bb.z;
    v.w = xr.w + f.w + bb.w;
    float s1 = v.x + v.y + v.z + v.w;
    float s2 = v.x * v.x + v.y * v.y + v.z * v.z + v.w * v.w;
    s1 = wave_reduce_sum(s1);
    s2 = wave_reduce_sum(s2);
    __shared__ float r1[2], r2[2];
    if (l == 0) { r1[wv] = s1; r2[wv] = s2; }
    __syncthreads();
    float S1 = r1[0] + r1[1], S2 = r2[0] + r2[1];
    float mu = S1 * (1.0f / HH);
    float var = S2 * (1.0f / HH) - mu * mu;
    float rs = rsqrtf(var + LN_EPS);
    float4 g4 = ((const float4*)ln_g)[tid];
    float4 b4 = ((const float4*)ln_b)[tid];
    float4 o;
    o.x = g4.x * (v.x - mu) * rs + b4.x;
    o.y = g4.y * (v.y - mu) * rs + b4.y;
    o.z = g4.z * (v.z - mu) * rs + b4.z;
    o.w = g4.w * (v.w - mu) * rs + b4.w;
    ((float4*)(out + (size_t)k * HH))[tid] = o;
}

extern "C" void kernel_launch(void* const* d_in, const int* in_sizes, int n_in,
                              void* d_out, int out_size, void* d_ws, size_t ws_size,
                              hipStream_t stream) {
    const float* x          = (const float*)d_in[0];
    const float* pair_feats = (const float*)d_in[1];
    const float* W_att      = (const float*)d_in[2];
    const float* b_att      = (const float*)d_in[3];
    const float* W_obj      = (const float*)d_in[4];
    const float* b_obj      = (const float*)d_in[5];
    const float* W_pair     = (const float*)d_in[6];
    const float* b_pair     = (const float*)d_in[7];
    const float* ln_g       = (const float*)d_in[8];
    const float* ln_b       = (const float*)d_in[9];
    const float* W1         = (const float*)d_in[10];
    const float* b1         = (const float*)d_in[11];
    const float* W2         = (const float*)d_in[12];
    const float* b2         = (const float*)d_in[13];
    float* out = (float*)d_out;

    const size_t MAT = (size_t)KK * HH;       // 262144
    float* ws        = (float*)d_ws;
    float* sa        = ws;                                  // 512
    float* sb        = sa + KK;                             // 512
    float* asum_part = sb + KK;                             // 4*512
    float* apf_part  = asum_part + NCHUNK * KK;             // 4*512*128
    float* msg       = apf_part + (size_t)NCHUNK * KK * PD; // MAT
    float* out1      = msg + MAT;                           // MAT
    float* ffn       = out1 + MAT;                          // MAT
    short* Ab        = (short*)(ffn + MAT);                 // MAT bf16
    short* xTb       = Ab + MAT;                            // MAT
    short* W_objb    = xTb + MAT;                           // MAT
    short* W_pairb   = W_objb + MAT;                        // 512*128
    short* W1b       = W_pairb + (size_t)HH * PD;           // MAT
    short* W2b       = W1b + MAT;                           // MAT
    short* yb        = W2b + MAT;                           // MAT
    short* out1b     = yb + MAT;                            // MAT
    short* h1b       = out1b + MAT;                         // MAT

    sab_kernel<<<128, 256, 0, stream>>>(x, W_att, sa, sb);
    pair_mega<<<2720, 512, 0, stream>>>(pair_feats, sa, sb, W_att, b_att,
                                        Ab, apf_part, asum_part,
                                        W_obj, W_pair, W1, W2,
                                        W_objb, W_pairb, W1b, W2b, x, xTb);
    k_y<<<dim3(16, 16), 128, 0, stream>>>(Ab, xTb, yb);
    k_msg<<<dim3(16, 16), 128, 0, stream>>>(yb, W_objb, apf_part, W_pairb, msg);
    ln1_kernel<<<512, 128, 0, stream>>>(msg, x, asum_part, b_pair, b_obj, ln_g, ln_b, out1, out1b);
    k_ffn1<<<dim3(16, 16), 128, 0, stream>>>(out1b, W1b, b1, h1b);
    k_ffn2<<<dim3(16, 16), 128, 0, stream>>>(h1b, W2b, ffn);
    ln2_kernel<<<512, 128, 0, stream>>>(ffn, out1, b2, ln_g, ln_b, out);
}